// Round 1
// 35.100 us; speedup vs baseline: 1.0174x; 1.0174x over previous
//
#include <hip/hip_runtime.h>
#include <cstdint>

// CharEmb: per word (B*S=16384): gather 32 char embeddings (E=64) -> x[64][32]
// (raw view of the [32 chars][64] buffer), conv1d(F=128,K=3,valid,T=30), bias,
// max over t. Output float32 [16384][128].
//
// MFMA formulation (32x32x16 bf16), M=t, N=f (VERIFIED, absmax 0.031):
//   D[t][f] = sum_kk sum_e xT[t+kk][e] * W[f][e][kk]
// - xT[c][e] staged in LDS bf16, row stride 72 elems (144 B, 16B-aligned).
// - conv shift t+kk = pure LDS address offset on the A-fragment read.
// - A frag: A[m=lane&31][k=(lane>>5)*8+j]; B frag: B[k][n=lane&31] (pre-packed).
// - C/D: col=lane&31, row=(reg&3)+8*(reg>>2)+4*(lane>>5); t=30,31 masked.
//
// Round 3: cut LDS A-read redundancy 2x. Each wave now owns TWO f-tiles
// (np = wv&1 -> f in [np*64, np*64+64)) and words are split by parity across
// wave pairs (ws = wv>>1). Each ds_read_b128 A-fragment feeds 2 MFMAs.
// A-reads/word: 48 -> 24. VGPR ~200 -> __launch_bounds__(256,2), 2 blk/CU.
// Also: cid loads hoisted to kernel start (16 regs), and staging split
// T14-style: emb gathers issue BEFORE the compute words, cvt+LDS-writes
// happen AFTER, so global latency hides under ~1550 cyc of MFMA.

typedef __bf16 bf16x8 __attribute__((ext_vector_type(8)));
typedef float  f32x16 __attribute__((ext_vector_type(16)));

#define GW   4    // words staged per barrier group
#define NGRP 4    // groups per block; 16 words/block, 1024 blocks
#define NW   16   // words per block
#define ROWS 34
#define RST  72   // row stride in bf16 elems (36 dwords)

// Pack conv_w [F=128][E=64][K=3] fp32 -> B-fragment-ordered bf16 in ws:
// pw[(((nt*3+kk)*4+ks)*64 + lane)*8 + j] = w[f=nt*32+(lane&31)][e=ks*16+(lane>>5)*8+j][kk]
__global__ __launch_bounds__(256)
void prep_pack_w(const float* __restrict__ w, __bf16* __restrict__ pw) {
  int i = blockIdx.x * 256 + threadIdx.x;   // 0..24575
  int j    = i & 7;
  int lane = (i >> 3) & 63;
  int ks   = (i >> 9) & 3;
  int t    = i >> 11;        // nt*3 + kk
  int kk   = t % 3;
  int nt   = t / 3;
  int f = nt * 32 + (lane & 31);
  int e = ks * 16 + (lane >> 5) * 8 + j;
  pw[i] = (__bf16)w[f * 192 + e * 3 + kk];
}

__global__ __launch_bounds__(256, 2)
void charcnn_mfma(const int* __restrict__ cid, const float* __restrict__ emb,
                  const float* __restrict__ bias, const __bf16* __restrict__ pw,
                  float* __restrict__ out) {
  // 8 word-buffers (two groups of 4), 34 rows x 72 bf16 = 4896 B each.
  __shared__ __align__(16) __bf16 xT[8][ROWS * RST];

  const int tid  = threadIdx.x;
  const int lane = tid & 63;
  const int wv   = tid >> 6;
  const int np   = wv & 1;    // f-tile pair: f in [np*64, np*64+64)
  const int ws   = wv >> 1;   // word parity this wave computes

  // persistent B fragments (weights) for TWO f-tiles: 24 frags = 96 VGPRs
  bf16x8 bfrag[2][12];
  const bf16x8* pwv = (const bf16x8*)pw;
#pragma unroll
  for (int nt = 0; nt < 2; ++nt)
#pragma unroll
    for (int q = 0; q < 12; ++q)        // q = kk*4 + ks
      bfrag[nt][q] = pwv[((np * 2 + nt) * 12 + q) * 64 + lane];

  const float vb0 = bias[(np * 2 + 0) * 32 + (lane & 31)];
  const float vb1 = bias[(np * 2 + 1) * 32 + (lane & 31)];

  // staging map: thread -> (char slot a, float4 pair p)
  const int a  = tid >> 3;            // 0..31 (char within word)
  const int p  = tid & 7;             // 0..7  (float4 index)
  const int d0 = p * 4;               // row base (c = d0..d0+3)
  const int bw = blockIdx.x * NW;

  // hoist ALL cid loads for this block: kills the cid->emb dependent stall
  int chw[NW];
#pragma unroll
  for (int w = 0; w < NW; ++w) chw[w] = cid[(bw + w) * 32 + a];

  // in-flight staged registers (T14 split: load early, write late)
  float4 slo[GW], shi[GW];

  auto stage_load = [&](int g) {
#pragma unroll
    for (int i = 0; i < GW; ++i) {
      const float4* er = (const float4*)(emb + chw[g * GW + i] * 64);
      slo[i] = er[p];         // c = d0..d0+3
      shi[i] = er[p + 8];     // c = d0..d0+3, upper 32 dims
    }
  };

  auto stage_write = [&](int g) {
    const int w0 = g * GW;
#pragma unroll
    for (int i = 0; i < GW; ++i) {
      uint32_t* dst = (uint32_t*)(&xT[(w0 + i) & 7][0]);
      float lv[4] = {slo[i].x, slo[i].y, slo[i].z, slo[i].w};
      float hv[4] = {shi[i].x, shi[i].y, shi[i].z, shi[i].w};
#pragma unroll
      for (int i2 = 0; i2 < 4; ++i2) {
        uint32_t u = ((uint32_t)__builtin_bit_cast(uint16_t, (__bf16)hv[i2]) << 16)
                   |  (uint32_t)__builtin_bit_cast(uint16_t, (__bf16)lv[i2]);
        dst[(d0 + i2) * 36 + a] = u;   // dword index: row*36 + colpair
      }
    }
  };

  // max over t. t = (reg&3) + 8*(reg>>2) + 4*(lane>>5).
  // upper half (lane>=32): regs 14,15 are t=30,31 -> excluded.
  auto finish = [&](const f32x16& acc, float vbv, int fcol, int w) {
    float m01 = fmaxf(acc[0],  acc[1]);
    float m23 = fmaxf(acc[2],  acc[3]);
    float m45 = fmaxf(acc[4],  acc[5]);
    float m67 = fmaxf(acc[6],  acc[7]);
    float m89 = fmaxf(acc[8],  acc[9]);
    float mab = fmaxf(acc[10], acc[11]);
    float mcd = fmaxf(acc[12], acc[13]);
    float q0 = fmaxf(m01, m23);
    float q1 = fmaxf(m45, m67);
    float q2 = fmaxf(m89, mab);
    float m0 = fmaxf(fmaxf(q0, q1), fmaxf(q2, mcd));
    float m1 = fmaxf(acc[14], acc[15]);
    float mm = (lane < 32) ? fmaxf(m0, m1) : m0;
    float other = __shfl_xor(mm, 32, 64);
    float fullmax = fmaxf(mm, other) + vbv;
    if (lane < 32) out[(bw + w) * 128 + fcol + lane] = fullmax;
  };

  auto compute_word = [&](int w) {
    const __bf16* xb = &xT[w & 7][0] + (lane & 31) * RST + (lane >> 5) * 8;
    f32x16 acc0, acc1;
#pragma unroll
    for (int r = 0; r < 16; ++r) { acc0[r] = 0.0f; acc1[r] = 0.0f; }

#pragma unroll
    for (int kk = 0; kk < 3; ++kk) {
#pragma unroll
      for (int ks = 0; ks < 4; ++ks) {
        // A[m][k] = xT[m+kk][ks*16 + (lane>>5)*8 + j], m = lane&31
        bf16x8 av = *(const bf16x8*)(xb + kk * RST + ks * 16);
        acc0 = __builtin_amdgcn_mfma_f32_32x32x16_bf16(av, bfrag[0][kk * 4 + ks],
                                                       acc0, 0, 0, 0);
        acc1 = __builtin_amdgcn_mfma_f32_32x32x16_bf16(av, bfrag[1][kk * 4 + ks],
                                                       acc1, 0, 0, 0);
      }
    }
    finish(acc0, vb0, np * 64,      w);
    finish(acc1, vb1, np * 64 + 32, w);
  };

  stage_load(0);
  stage_write(0);
  __syncthreads();

#pragma unroll
  for (int g = 0; g < NGRP; ++g) {
    if (g + 1 < NGRP) stage_load(g + 1);    // emb gathers issue early
    compute_word(g * GW + ws);              // this wave's 2 words of the group
    compute_word(g * GW + ws + 2);
    if (g + 1 < NGRP) stage_write(g + 1);   // cvt + LDS writes after compute
    if (g + 1 < NGRP) __syncthreads();
  }
}

extern "C" void kernel_launch(void* const* d_in, const int* in_sizes, int n_in,
                              void* d_out, int out_size, void* d_ws, size_t ws_size,
                              hipStream_t stream) {
  const int*   cid = (const int*)d_in[0];    // [32*512*32] int32
  const float* emb = (const float*)d_in[1];  // [101*64]  f32
  const float* cw  = (const float*)d_in[2];  // [128*64*3] f32
  const float* cb  = (const float*)d_in[3];  // [128] f32
  float* outp = (float*)d_out;               // [16384*128] f32
  __bf16* pw = (__bf16*)d_ws;                // 24576 bf16 = 48 KB

  hipLaunchKernelGGL(prep_pack_w, dim3(96), dim3(256), 0, stream, cw, pw);
  hipLaunchKernelGGL(charcnn_mfma, dim3(1024), dim3(256), 0, stream,
                     cid, emb, cb, (const __bf16*)pw, outp);
}